// Round 11
// baseline (186.600 us; speedup 1.0000x reference)
//
#include <hip/hip_runtime.h>
#include <hip/hip_bf16.h>
#include <math.h>

typedef __bf16 bf16x8 __attribute__((ext_vector_type(8)));
typedef unsigned short u16x8 __attribute__((ext_vector_type(8)));
typedef unsigned short u16x4 __attribute__((ext_vector_type(4)));
typedef float f32x4 __attribute__((ext_vector_type(4)));
typedef unsigned int u32x4 __attribute__((ext_vector_type(4)));
typedef unsigned int u32x2 __attribute__((ext_vector_type(2)));
typedef unsigned short u16;

__device__ __forceinline__ u16 f2bf(float f) {   // round-to-nearest-even
    unsigned int x = __float_as_uint(f);
    x += 0x7fffu + ((x >> 16) & 1u);
    return (u16)(x >> 16);
}
__device__ __forceinline__ void glds16(const void* g, void* l) {
    __builtin_amdgcn_global_load_lds(
        (const __attribute__((address_space(1))) void*)g,
        (__attribute__((address_space(3))) void*)l, 16, 0, 0);
}
// permlane32_swap then permlane16_swap: (a,b) = (w[t][h], w[t+1][h]) -> (dword m0, dword m2)
// of the PV A-fragment (16x16x32 layout: lane(l15,quad) row=l15, k=quad*8..+7).
__device__ __forceinline__ void swap_half(unsigned& a, unsigned& b) {
    u32x2 t = __builtin_amdgcn_permlane32_swap(a, b, false, false);
    t = __builtin_amdgcn_permlane16_swap(t[0], t[1], false, false);
    a = t[0]; b = t[1];
}

// ---------------- prep: z<4: fp32 W[k][n] -> bf16 Wt[n][k]; z>=4: x fp32 -> bf16 copy ----
__global__ __launch_bounds__(256) void prep(const float* __restrict__ W0, const float* __restrict__ W1,
                                            const float* __restrict__ W2, const float* __restrict__ W3,
                                            const float* __restrict__ X,
                                            u16* __restrict__ Wt, u16* __restrict__ Xb) {
    int z = blockIdx.z;
    if (z >= 4) {
        int row = (z - 4) * 1024 + blockIdx.y * 32 + blockIdx.x;
        const float* src = X + (size_t)row * 1024 + threadIdx.x * 4;
        f32x4 v = *(const f32x4*)src;
        u16x4 o; o[0] = f2bf(v[0]); o[1] = f2bf(v[1]); o[2] = f2bf(v[2]); o[3] = f2bf(v[3]);
        *(u16x4*)&Xb[(size_t)row * 1024 + threadIdx.x * 4] = o;
        return;
    }
    __shared__ float T[32][33];
    const float* W = (z == 0) ? W0 : ((z == 1) ? W1 : ((z == 2) ? W2 : W3));
    u16* dst = Wt + (size_t)z * 1024 * 1024;
    int k0 = blockIdx.y * 32, n0 = blockIdx.x * 32;
    int x = threadIdx.x & 31, y0 = threadIdx.x >> 5;
#pragma unroll
    for (int i = 0; i < 4; i++) {
        int y = y0 + i * 8;
        T[y][x] = W[(size_t)(k0 + y) * 1024 + n0 + x];
    }
    __syncthreads();
#pragma unroll
    for (int i = 0; i < 4; i++) {
        int y = y0 + i * 8;
        dst[(size_t)(n0 + y) * 1024 + k0 + x] = f2bf(T[x][y]);
    }
}

// ---------------- gemm256: QKV GEMM, 256x192 tile, BK=64, 8-wave 8-phase schedule ----
// (byte-identical to R9/R10 — verified) full-fill 256-block grid, per-16-col-group epilogue.
__global__ __launch_bounds__(512, 2) void gemm256(
    const u16* __restrict__ Bt,
    const float* __restrict__ b0, const float* __restrict__ b1, const float* __restrict__ b2,
    const u16* __restrict__ A, u16* __restrict__ C, u16* __restrict__ Vt)
{
    __shared__ __align__(16) u16 As[2][256 * 64];   // 64 KB
    __shared__ __align__(16) u16 Bs[2][192 * 64];   // 48 KB
    int tid = threadIdx.x;
    int lane = tid & 63, l15 = lane & 15, quad = lane >> 4;
    int wid = tid >> 6;                 // 0..7
    int wm = wid >> 2, wn = wid & 3;    // 2 (M) x 4 (N)
    int lin = blockIdx.x;               // 0..255
    int xcd = lin & 7, idx = lin >> 3;  // idx 0..31
    int mtile = (xcd >> 1) * 4 + (idx & 3);    // 0..15
    int ntile = (xcd & 1) * 8 + (idx >> 2);    // 0..15
    int m0 = mtile * 256, n0 = ntile * 192;

    f32x4 acc[8][3];
#pragma unroll
    for (int i = 0; i < 8; i++)
#pragma unroll
        for (int j = 0; j < 3; j++) { f32x4 z = {0.f, 0.f, 0.f, 0.f}; acc[i][j] = z; }

    int rr = lane >> 3;                 // row within 8-row glds inst
    int cc = (lane & 7) ^ rr;           // pre-swizzled global chunk
    int fs7 = l15 & 7;                  // frag un-swizzle key
    const u16* abase = A  + (size_t)m0 * 1024;
    const u16* bbase = Bt + (size_t)n0 * 1024;

    auto stage = [&](int kt, int hp, int buf) {
        int k0 = kt * 64;
        if (hp < 2) {
            int hbase = hp * 128;
#pragma unroll
            for (int inst = 0; inst < 2; inst++) {
                int r0 = hbase + wid * 16 + inst * 8;
                glds16(&abase[(size_t)(r0 + rr) * 1024 + k0 + cc * 8], &As[buf][r0 * 64]);
            }
        } else {
#pragma unroll
            for (int inst = 0; inst < 3; inst++) {
                int r0 = wid * 24 + inst * 8;
                glds16(&bbase[(size_t)(r0 + rr) * 1024 + k0 + cc * 8], &Bs[buf][r0 * 64]);
            }
        }
    };

    stage(0, 0, 0); stage(0, 1, 0); stage(0, 2, 0);   // prologue: 7 loads in flight

#pragma unroll 2
    for (int it = 0; it < 16; ++it) {
        int c = it & 1;
        if (it < 15) {
            stage(it + 1, 0, c ^ 1);
            asm volatile("s_waitcnt vmcnt(2)");
        } else {
            asm volatile("s_waitcnt vmcnt(0)");
        }
        __builtin_amdgcn_s_barrier();
        bf16x8 bfr[3][2];
#pragma unroll
        for (int nt = 0; nt < 3; nt++)
#pragma unroll
            for (int h = 0; h < 2; h++)
                bfr[nt][h] = *(const bf16x8*)&Bs[c][(wn * 48 + nt * 16 + l15) * 64 +
                                                    ((((h << 2) | quad) ^ fs7) * 8)];
        {
            bf16x8 af[2][2];
#pragma unroll
            for (int m = 0; m < 2; m++)
#pragma unroll
                for (int h = 0; h < 2; h++)
                    af[m][h] = *(const bf16x8*)&As[c][(wm * 128 + m * 16 + l15) * 64 +
                                                      ((((h << 2) | quad) ^ fs7) * 8)];
            asm volatile("s_waitcnt lgkmcnt(0)");
            __builtin_amdgcn_sched_barrier(0);
            __builtin_amdgcn_s_setprio(1);
#pragma unroll
            for (int m = 0; m < 2; m++)
#pragma unroll
                for (int nt = 0; nt < 3; nt++)
#pragma unroll
                    for (int h = 0; h < 2; h++)
                        acc[m][nt] = __builtin_amdgcn_mfma_f32_16x16x32_bf16(
                            af[m][h], bfr[nt][h], acc[m][nt], 0, 0, 0);
            __builtin_amdgcn_s_setprio(0);
            __builtin_amdgcn_s_barrier();
        }
#pragma unroll
        for (int p = 1; p < 4; p++) {
            bf16x8 af[2][2];
#pragma unroll
            for (int m = 0; m < 2; m++)
#pragma unroll
                for (int h = 0; h < 2; h++)
                    af[m][h] = *(const bf16x8*)&As[c][(wm * 128 + (p * 2 + m) * 16 + l15) * 64 +
                                                      ((((h << 2) | quad) ^ fs7) * 8)];
            if (it < 15 && p < 3) stage(it + 1, p, c ^ 1);
            __builtin_amdgcn_s_barrier();
            asm volatile("s_waitcnt lgkmcnt(0)");
            __builtin_amdgcn_sched_barrier(0);
            __builtin_amdgcn_s_setprio(1);
#pragma unroll
            for (int m = 0; m < 2; m++)
#pragma unroll
                for (int nt = 0; nt < 3; nt++)
#pragma unroll
                    for (int h = 0; h < 2; h++)
                        acc[p * 2 + m][nt] = __builtin_amdgcn_mfma_f32_16x16x32_bf16(
                            af[m][h], bfr[nt][h], acc[p * 2 + m][nt], 0, 0, 0);
            __builtin_amdgcn_s_setprio(0);
            __builtin_amdgcn_s_barrier();
        }
    }

    int bb_ = m0 >> 11;   // batch
#pragma unroll
    for (int nt = 0; nt < 3; nt++) {
        int gc0 = n0 + wn * 48 + nt * 16;            // group base, 16-aligned
        int seg = gc0 >> 10;
        const float* bias = (seg == 0) ? b0 : ((seg == 1) ? b1 : b2);
        int gcl = (gc0 & 1023) + l15;                // column within segment
        float bv = bias[gcl];
        if (seg == 2) {
#pragma unroll
            for (int mt = 0; mt < 8; mt++) {
                int gr = m0 + wm * 128 + mt * 16 + quad * 4;
                int s = gr & 2047;
                u16x4 pk;
#pragma unroll
                for (int r = 0; r < 4; r++) pk[r] = f2bf(acc[mt][nt][r] + bv);
                *(u16x4*)&Vt[(size_t)((bb_ * 16 + (gcl >> 6)) * 64 + (gcl & 63)) * 2048 + s] = pk;
            }
        } else {
            float qs = (seg == 0) ? 0.18033688011112f : 1.0f;  // log2(e)/sqrt(64)
            int gc = gc0 + l15;
#pragma unroll
            for (int mt = 0; mt < 8; mt++) {
                int gr = m0 + wm * 128 + mt * 16 + quad * 4;
#pragma unroll
                for (int r = 0; r < 4; r++)
                    C[(size_t)(gr + r) * 3072 + gc] = f2bf((acc[mt][nt][r] + bv) * qs);
            }
        }
    }
}

// ---------------- gemmo (output proj): 128x64 tile, 2-phase, 512 blocks = 2/CU ----------
// (byte-identical to R10 — verified)
__global__ __launch_bounds__(256) void gemmo(
    const u16* __restrict__ Bt, const float* __restrict__ bias,
    const u16* __restrict__ A, float* __restrict__ C)
{
    __shared__ __align__(16) u16 As[128 * 32];
    __shared__ __align__(16) u16 Bs[64 * 32];
    int tid = threadIdx.x;
    int lane = tid & 63, l15 = lane & 15, quad = lane >> 4;
    int wid = tid >> 6, wm = wid >> 1, wn = wid & 1;
    int lin = blockIdx.x;               // 0..511
    int xcd = lin & 7, idx = lin >> 3;  // idx 0..63
    int mtile = (xcd >> 1) * 8 + (idx & 7);    // 0..31
    int ntile = (xcd & 1) * 8 + (idx >> 3);    // 0..15
    int m0 = mtile * 128, n0 = ntile * 64;

    f32x4 acc[4][2];
#pragma unroll
    for (int i = 0; i < 4; i++)
#pragma unroll
        for (int j = 0; j < 2; j++) { f32x4 z = {0.f, 0.f, 0.f, 0.f}; acc[i][j] = z; }

    int rr = lane >> 2;                       // row within 16-row glds inst
    int cc = (lane & 3) ^ ((rr >> 1) & 3);    // swizzled global chunk
    const u16* abase = A  + (size_t)m0 * 1024;
    const u16* bbase = Bt + (size_t)n0 * 1024;
    int fsw = (l15 >> 1) & 3;                 // frag un-swizzle key

    for (int k0 = 0; k0 < 1024; k0 += 32) {
#pragma unroll
        for (int inst = 0; inst < 2; inst++) {
            int r0 = wid * 32 + inst * 16;
            glds16(&abase[(size_t)(r0 + rr) * 1024 + k0 + cc * 8], &As[r0 * 32]);
        }
        {
            int r0 = wid * 16;
            glds16(&bbase[(size_t)(r0 + rr) * 1024 + k0 + cc * 8], &Bs[r0 * 32]);
        }
        __syncthreads();
        bf16x8 af[4], bf[2];
#pragma unroll
        for (int mt = 0; mt < 4; mt++)
            af[mt] = *(const bf16x8*)&As[(wm * 64 + mt * 16 + l15) * 32 + ((quad ^ fsw) * 8)];
#pragma unroll
        for (int nt = 0; nt < 2; nt++)
            bf[nt] = *(const bf16x8*)&Bs[(wn * 32 + nt * 16 + l15) * 32 + ((quad ^ fsw) * 8)];
#pragma unroll
        for (int mt = 0; mt < 4; mt++)
#pragma unroll
            for (int nt = 0; nt < 2; nt++)
                acc[mt][nt] = __builtin_amdgcn_mfma_f32_16x16x32_bf16(af[mt], bf[nt], acc[mt][nt], 0, 0, 0);
        __syncthreads();
    }
#pragma unroll
    for (int mt = 0; mt < 4; mt++) {
        int gr = m0 + wm * 64 + mt * 16 + quad * 4;
#pragma unroll
        for (int nt = 0; nt < 2; nt++) {
            int gc = n0 + wn * 32 + nt * 16 + l15;
            float bb = bias[gc];
#pragma unroll
            for (int r = 0; r < 4; r++)
                C[(size_t)(gr + r) * 1024 + gc] = acc[mt][nt][r] + bb;
        }
    }
}

// ---------------- MFMA flash attention, v7: v5 + zf-C qk + split psum ----------------
// Changes vs v5 (R10):
//  * qk: first MFMA of each chain takes constant-zero C (zf) -> no 8x f32x4 re-zero
//    (-32 v_mov/iter/wave; numerically exact, compile-verified in R7's kernel).
//  * psum split into two independent accumulators per half (psA0/psA1) -> serial
//    add-chain depth halves; merged once before the final reduction.
// Everything else identical: T15 double-pipeline, 4-buf, 2-ahead vmcnt(4), one
// barrier/iter, XCD-bijective remap, f32 denominator (R7 lesson: keep f32).
__global__ __launch_bounds__(256, 2) void attn(const u16* __restrict__ QKV, // [B*S][3072]
                                               const u16* __restrict__ Vt,  // [bh*64+d][2048]
                                               u16* __restrict__ O)         // [B*S][1024]
{
    __shared__ __align__(16) u16 Ks[4][64 * 64];  // [buf][j][d], XOR-swizzled chunks
    __shared__ __align__(16) u16 Vs[4][64 * 64];  // [buf][d][j], XOR-swizzled chunks
    const int S = 2048, DQ = 3072;
    int tid = threadIdx.x, wid = tid >> 6, lane = tid & 63;
    int l15 = lane & 15, quad = lane >> 4;
    int lin = blockIdx.x;
    int xcd = lin & 7;
    int rest = lin >> 3;            // 0..63
    int qt = rest & 15;
    int g = xcd + 8 * (rest >> 4);  // 0..31
    int h = g & 15, b = g >> 4;
    const u16* base = QKV + (size_t)b * S * DQ + h * 64;
    const u16* Kb = base + 1024;
    const u16* Vtb = Vt + (size_t)((b * 16 + h) * 64) * 2048;
    int q0 = qt * 128 + wid * 32;

    bf16x8 qA0 = *(const bf16x8*)&base[(size_t)(q0 + l15) * DQ + quad * 8];
    bf16x8 qA1 = *(const bf16x8*)&base[(size_t)(q0 + l15) * DQ + 32 + quad * 8];
    bf16x8 qB0 = *(const bf16x8*)&base[(size_t)(q0 + 16 + l15) * DQ + quad * 8];
    bf16x8 qB1 = *(const bf16x8*)&base[(size_t)(q0 + 16 + l15) * DQ + 32 + quad * 8];

    f32x4 oA[4], oB[4];
    const f32x4 zf = {0.f, 0.f, 0.f, 0.f};
#pragma unroll
    for (int i = 0; i < 4; i++) { oA[i] = zf; oB[i] = zf; }
    float psA0 = 0.f, psA1 = 0.f, psB0 = 0.f, psB1 = 0.f;

    int rr = lane >> 3;
    int cc = (lane & 7) ^ rr;
    int fs7 = l15 & 7;

    auto stage = [&](int t) {
        int kv0 = t << 6, bsel = t & 3;
#pragma unroll
        for (int inst = 0; inst < 2; inst++) {
            int r0 = wid * 16 + inst * 8;
            glds16(&Kb[(size_t)(kv0 + r0 + rr) * DQ + cc * 8], &Ks[bsel][r0 * 64]);
            glds16(&Vtb[(size_t)(r0 + rr) * 2048 + kv0 + cc * 8], &Vs[bsel][r0 * 64]);
        }
    };

    auto qk = [&](int i, f32x4* s) {
        const u16* Kc = &Ks[i & 3][0];
        bf16x8 kfa[4], kfb[4];
#pragma unroll
        for (int t = 0; t < 4; t++) {
            kfa[t] = *(const bf16x8*)&Kc[(t * 16 + l15) * 64 + ((quad ^ fs7) * 8)];
            kfb[t] = *(const bf16x8*)&Kc[(t * 16 + l15) * 64 + (((quad + 4) ^ fs7) * 8)];
        }
        __builtin_amdgcn_s_setprio(1);
#pragma unroll
        for (int t = 0; t < 4; t++) {
            s[t]     = __builtin_amdgcn_mfma_f32_16x16x32_bf16(kfa[t], qA0, zf, 0, 0, 0);
            s[t]     = __builtin_amdgcn_mfma_f32_16x16x32_bf16(kfb[t], qA1, s[t], 0, 0, 0);
            s[4 + t] = __builtin_amdgcn_mfma_f32_16x16x32_bf16(kfa[t], qB0, zf, 0, 0, 0);
            s[4 + t] = __builtin_amdgcn_mfma_f32_16x16x32_bf16(kfb[t], qB1, s[4 + t], 0, 0, 0);
        }
        __builtin_amdgcn_s_setprio(0);
    };

    auto fin = [&](int i, f32x4* s) {
        const u16* Vc = &Vs[i & 3][0];
        bf16x8 vfa[4], vfb[4];
#pragma unroll
        for (int dt = 0; dt < 4; dt++) {
            vfa[dt] = *(const bf16x8*)&Vc[(dt * 16 + l15) * 64 + ((quad ^ fs7) * 8)];
            vfb[dt] = *(const bf16x8*)&Vc[(dt * 16 + l15) * 64 + (((quad + 4) ^ fs7) * 8)];
        }
        unsigned wA[4][2], wB[4][2];
#pragma unroll
        for (int t = 0; t < 4; t++) {
            float a0 = __builtin_amdgcn_exp2f(s[t][0]);
            float a1 = __builtin_amdgcn_exp2f(s[t][1]);
            float a2 = __builtin_amdgcn_exp2f(s[t][2]);
            float a3 = __builtin_amdgcn_exp2f(s[t][3]);
            if (t & 1) psA1 += (a0 + a1) + (a2 + a3);
            else       psA0 += (a0 + a1) + (a2 + a3);
            asm("v_cvt_pk_bf16_f32 %0, %1, %2" : "=v"(wA[t][0]) : "v"(a0), "v"(a1));
            asm("v_cvt_pk_bf16_f32 %0, %1, %2" : "=v"(wA[t][1]) : "v"(a2), "v"(a3));
            float b0_ = __builtin_amdgcn_exp2f(s[4 + t][0]);
            float b1_ = __builtin_amdgcn_exp2f(s[4 + t][1]);
            float b2_ = __builtin_amdgcn_exp2f(s[4 + t][2]);
            float b3_ = __builtin_amdgcn_exp2f(s[4 + t][3]);
            if (t & 1) psB1 += (b0_ + b1_) + (b2_ + b3_);
            else       psB0 += (b0_ + b1_) + (b2_ + b3_);
            asm("v_cvt_pk_bf16_f32 %0, %1, %2" : "=v"(wB[t][0]) : "v"(b0_), "v"(b1_));
            asm("v_cvt_pk_bf16_f32 %0, %1, %2" : "=v"(wB[t][1]) : "v"(b2_), "v"(b3_));
        }
        unsigned a0 = wA[0][0], a2 = wA[1][0]; swap_half(a0, a2);
        unsigned a1 = wA[0][1], a3 = wA[1][1]; swap_half(a1, a3);
        unsigned c0 = wA[2][0], c2 = wA[3][0]; swap_half(c0, c2);
        unsigned c1 = wA[2][1], c3 = wA[3][1]; swap_half(c1, c3);
        u32x4 pdA0 = {a0, a1, a2, a3};
        u32x4 pdA1 = {c0, c1, c2, c3};
        bf16x8 pfA0 = *(bf16x8*)&pdA0;   // P_A[q=l15][j = quad*8 .. +7]
        bf16x8 pfA1 = *(bf16x8*)&pdA1;   // P_A[q=l15][j = 32+quad*8 .. +7]
        unsigned d0 = wB[0][0], d2 = wB[1][0]; swap_half(d0, d2);
        unsigned d1 = wB[0][1], d3 = wB[1][1]; swap_half(d1, d3);
        unsigned e0 = wB[2][0], e2 = wB[3][0]; swap_half(e0, e2);
        unsigned e1 = wB[2][1], e3 = wB[3][1]; swap_half(e1, e3);
        u32x4 pdB0 = {d0, d1, d2, d3};
        u32x4 pdB1 = {e0, e1, e2, e3};
        bf16x8 pfB0 = *(bf16x8*)&pdB0;
        bf16x8 pfB1 = *(bf16x8*)&pdB1;
        __builtin_amdgcn_s_setprio(1);
#pragma unroll
        for (int dt = 0; dt < 4; dt++) {
            oA[dt] = __builtin_amdgcn_mfma_f32_16x16x32_bf16(pfA0, vfa[dt], oA[dt], 0, 0, 0);
            oA[dt] = __builtin_amdgcn_mfma_f32_16x16x32_bf16(pfA1, vfb[dt], oA[dt], 0, 0, 0);
            oB[dt] = __builtin_amdgcn_mfma_f32_16x16x32_bf16(pfB0, vfa[dt], oB[dt], 0, 0, 0);
            oB[dt] = __builtin_amdgcn_mfma_f32_16x16x32_bf16(pfB1, vfb[dt], oB[dt], 0, 0, 0);
        }
        __builtin_amdgcn_s_setprio(0);
    };

    f32x4 sE[8], sO[8];               // two named S-states (even/odd tiles)

    stage(0); stage(1);               // prologue: tiles 0,1 in flight (8 loads)
    asm volatile("s_waitcnt vmcnt(4)");   // tile 0 landed, tile 1 in flight
    __builtin_amdgcn_s_barrier();
    stage(2);
    qk(0, sE);
    for (int j = 0; j < 15; ++j) {
        int i = 2 * j + 1;
        asm volatile("s_waitcnt vmcnt(4)");
        __builtin_amdgcn_s_barrier();
        if (i + 2 < 32) stage(i + 2);
        qk(i, sO);
        fin(i - 1, sE);
        asm volatile("s_waitcnt vmcnt(4)");
        __builtin_amdgcn_s_barrier();
        if (i + 3 < 32) stage(i + 3);
        qk(i + 1, sE);
        fin(i, sO);
    }
    asm volatile("s_waitcnt vmcnt(0)");
    __builtin_amdgcn_s_barrier();
    qk(31, sO);
    fin(30, sE);
    fin(31, sO);                      // epilogue

    float psA = psA0 + psA1;
    float psB = psB0 + psB1;
    psA += __shfl_xor(psA, 16);
    psA += __shfl_xor(psA, 32);
    psB += __shfl_xor(psB, 16);
    psB += __shfl_xor(psB, 32);
#pragma unroll
    for (int r = 0; r < 4; r++) {
        float invA = 1.0f / __shfl(psA, quad * 4 + r);
        size_t rowA = (size_t)(b * S + q0 + quad * 4 + r);
#pragma unroll
        for (int dt = 0; dt < 4; dt++)
            O[rowA * 1024 + h * 64 + dt * 16 + l15] = f2bf(oA[dt][r] * invA);
        float invB = 1.0f / __shfl(psB, quad * 4 + r);
        size_t rowB = rowA + 16;
#pragma unroll
        for (int dt = 0; dt < 4; dt++)
            O[rowB * 1024 + h * 64 + dt * 16 + l15] = f2bf(oB[dt][r] * invB);
    }
}

extern "C" void kernel_launch(void* const* d_in, const int* in_sizes, int n_in,
                              void* d_out, int out_size, void* d_ws, size_t ws_size,
                              hipStream_t stream) {
    const float* x  = (const float*)d_in[0];
    const float* wq = (const float*)d_in[1];
    const float* bq = (const float*)d_in[2];
    const float* wk = (const float*)d_in[3];
    const float* bk = (const float*)d_in[4];
    const float* wv = (const float*)d_in[5];
    const float* bv = (const float*)d_in[6];
    const float* wo = (const float*)d_in[7];
    const float* bo = (const float*)d_in[8];
    float* out = (float*)d_out;

    u16* qkv  = (u16*)d_ws;
    u16* obuf = qkv  + (size_t)4096 * 3072;
    u16* vt   = obuf + (size_t)4096 * 1024;
    u16* wt   = vt   + (size_t)2048 * 2048;
    u16* xb   = wt   + (size_t)4 * 1024 * 1024;

    dim3 tb(256);
    prep<<<dim3(32, 32, 8), tb, 0, stream>>>(wq, wk, wv, wo, x, wt, xb);
    gemm256<<<dim3(256), dim3(512), 0, stream>>>(wt, bq, bk, bv, xb, qkv, vt);
    attn<<<dim3(512), tb, 0, stream>>>(qkv, vt, obuf);
    gemmo<<<dim3(512), tb, 0, stream>>>(wt + (size_t)3 * 1024 * 1024, bo, obuf, out);
}

// Round 12
// 183.129 us; speedup vs baseline: 1.0190x; 1.0190x over previous
//
#include <hip/hip_runtime.h>
#include <hip/hip_bf16.h>
#include <math.h>

typedef __bf16 bf16x8 __attribute__((ext_vector_type(8)));
typedef unsigned short u16x8 __attribute__((ext_vector_type(8)));
typedef unsigned short u16x4 __attribute__((ext_vector_type(4)));
typedef float f32x4 __attribute__((ext_vector_type(4)));
typedef unsigned int u32x4 __attribute__((ext_vector_type(4)));
typedef unsigned int u32x2 __attribute__((ext_vector_type(2)));
typedef unsigned short u16;

__device__ __forceinline__ u16 f2bf(float f) {   // round-to-nearest-even
    unsigned int x = __float_as_uint(f);
    x += 0x7fffu + ((x >> 16) & 1u);
    return (u16)(x >> 16);
}
__device__ __forceinline__ void glds16(const void* g, void* l) {
    __builtin_amdgcn_global_load_lds(
        (const __attribute__((address_space(1))) void*)g,
        (__attribute__((address_space(3))) void*)l, 16, 0, 0);
}
// permlane32_swap then permlane16_swap: (a,b) = (w[t][h], w[t+1][h]) -> (dword m0, dword m2)
// of the PV A-fragment (16x16x32 layout: lane(l15,quad) row=l15, k=quad*8..+7).
__device__ __forceinline__ void swap_half(unsigned& a, unsigned& b) {
    u32x2 t = __builtin_amdgcn_permlane32_swap(a, b, false, false);
    t = __builtin_amdgcn_permlane16_swap(t[0], t[1], false, false);
    a = t[0]; b = t[1];
}

// ---------------- prep: z<4: fp32 W[k][n] -> bf16 Wt[n][k]; z>=4: x fp32 -> bf16 copy ----
__global__ __launch_bounds__(256) void prep(const float* __restrict__ W0, const float* __restrict__ W1,
                                            const float* __restrict__ W2, const float* __restrict__ W3,
                                            const float* __restrict__ X,
                                            u16* __restrict__ Wt, u16* __restrict__ Xb) {
    int z = blockIdx.z;
    if (z >= 4) {
        int row = (z - 4) * 1024 + blockIdx.y * 32 + blockIdx.x;
        const float* src = X + (size_t)row * 1024 + threadIdx.x * 4;
        f32x4 v = *(const f32x4*)src;
        u16x4 o; o[0] = f2bf(v[0]); o[1] = f2bf(v[1]); o[2] = f2bf(v[2]); o[3] = f2bf(v[3]);
        *(u16x4*)&Xb[(size_t)row * 1024 + threadIdx.x * 4] = o;
        return;
    }
    __shared__ float T[32][33];
    const float* W = (z == 0) ? W0 : ((z == 1) ? W1 : ((z == 2) ? W2 : W3));
    u16* dst = Wt + (size_t)z * 1024 * 1024;
    int k0 = blockIdx.y * 32, n0 = blockIdx.x * 32;
    int x = threadIdx.x & 31, y0 = threadIdx.x >> 5;
#pragma unroll
    for (int i = 0; i < 4; i++) {
        int y = y0 + i * 8;
        T[y][x] = W[(size_t)(k0 + y) * 1024 + n0 + x];
    }
    __syncthreads();
#pragma unroll
    for (int i = 0; i < 4; i++) {
        int y = y0 + i * 8;
        dst[(size_t)(n0 + y) * 1024 + k0 + x] = f2bf(T[x][y]);
    }
}

// ---------------- gemm256: QKV GEMM, 256x192 tile, BK=64, 8-wave 8-phase schedule ----
// (byte-identical to R9/R10 — verified) full-fill 256-block grid, per-16-col-group epilogue.
__global__ __launch_bounds__(512, 2) void gemm256(
    const u16* __restrict__ Bt,
    const float* __restrict__ b0, const float* __restrict__ b1, const float* __restrict__ b2,
    const u16* __restrict__ A, u16* __restrict__ C, u16* __restrict__ Vt)
{
    __shared__ __align__(16) u16 As[2][256 * 64];   // 64 KB
    __shared__ __align__(16) u16 Bs[2][192 * 64];   // 48 KB
    int tid = threadIdx.x;
    int lane = tid & 63, l15 = lane & 15, quad = lane >> 4;
    int wid = tid >> 6;                 // 0..7
    int wm = wid >> 2, wn = wid & 3;    // 2 (M) x 4 (N)
    int lin = blockIdx.x;               // 0..255
    int xcd = lin & 7, idx = lin >> 3;  // idx 0..31
    int mtile = (xcd >> 1) * 4 + (idx & 3);    // 0..15
    int ntile = (xcd & 1) * 8 + (idx >> 2);    // 0..15
    int m0 = mtile * 256, n0 = ntile * 192;

    f32x4 acc[8][3];
#pragma unroll
    for (int i = 0; i < 8; i++)
#pragma unroll
        for (int j = 0; j < 3; j++) { f32x4 z = {0.f, 0.f, 0.f, 0.f}; acc[i][j] = z; }

    int rr = lane >> 3;                 // row within 8-row glds inst
    int cc = (lane & 7) ^ rr;           // pre-swizzled global chunk
    int fs7 = l15 & 7;                  // frag un-swizzle key
    const u16* abase = A  + (size_t)m0 * 1024;
    const u16* bbase = Bt + (size_t)n0 * 1024;

    auto stage = [&](int kt, int hp, int buf) {
        int k0 = kt * 64;
        if (hp < 2) {
            int hbase = hp * 128;
#pragma unroll
            for (int inst = 0; inst < 2; inst++) {
                int r0 = hbase + wid * 16 + inst * 8;
                glds16(&abase[(size_t)(r0 + rr) * 1024 + k0 + cc * 8], &As[buf][r0 * 64]);
            }
        } else {
#pragma unroll
            for (int inst = 0; inst < 3; inst++) {
                int r0 = wid * 24 + inst * 8;
                glds16(&bbase[(size_t)(r0 + rr) * 1024 + k0 + cc * 8], &Bs[buf][r0 * 64]);
            }
        }
    };

    stage(0, 0, 0); stage(0, 1, 0); stage(0, 2, 0);   // prologue: 7 loads in flight

#pragma unroll 2
    for (int it = 0; it < 16; ++it) {
        int c = it & 1;
        if (it < 15) {
            stage(it + 1, 0, c ^ 1);
            asm volatile("s_waitcnt vmcnt(2)");
        } else {
            asm volatile("s_waitcnt vmcnt(0)");
        }
        __builtin_amdgcn_s_barrier();
        bf16x8 bfr[3][2];
#pragma unroll
        for (int nt = 0; nt < 3; nt++)
#pragma unroll
            for (int h = 0; h < 2; h++)
                bfr[nt][h] = *(const bf16x8*)&Bs[c][(wn * 48 + nt * 16 + l15) * 64 +
                                                    ((((h << 2) | quad) ^ fs7) * 8)];
        {
            bf16x8 af[2][2];
#pragma unroll
            for (int m = 0; m < 2; m++)
#pragma unroll
                for (int h = 0; h < 2; h++)
                    af[m][h] = *(const bf16x8*)&As[c][(wm * 128 + m * 16 + l15) * 64 +
                                                      ((((h << 2) | quad) ^ fs7) * 8)];
            asm volatile("s_waitcnt lgkmcnt(0)");
            __builtin_amdgcn_sched_barrier(0);
            __builtin_amdgcn_s_setprio(1);
#pragma unroll
            for (int m = 0; m < 2; m++)
#pragma unroll
                for (int nt = 0; nt < 3; nt++)
#pragma unroll
                    for (int h = 0; h < 2; h++)
                        acc[m][nt] = __builtin_amdgcn_mfma_f32_16x16x32_bf16(
                            af[m][h], bfr[nt][h], acc[m][nt], 0, 0, 0);
            __builtin_amdgcn_s_setprio(0);
            __builtin_amdgcn_s_barrier();
        }
#pragma unroll
        for (int p = 1; p < 4; p++) {
            bf16x8 af[2][2];
#pragma unroll
            for (int m = 0; m < 2; m++)
#pragma unroll
                for (int h = 0; h < 2; h++)
                    af[m][h] = *(const bf16x8*)&As[c][(wm * 128 + (p * 2 + m) * 16 + l15) * 64 +
                                                      ((((h << 2) | quad) ^ fs7) * 8)];
            if (it < 15 && p < 3) stage(it + 1, p, c ^ 1);
            __builtin_amdgcn_s_barrier();
            asm volatile("s_waitcnt lgkmcnt(0)");
            __builtin_amdgcn_sched_barrier(0);
            __builtin_amdgcn_s_setprio(1);
#pragma unroll
            for (int m = 0; m < 2; m++)
#pragma unroll
                for (int nt = 0; nt < 3; nt++)
#pragma unroll
                    for (int h = 0; h < 2; h++)
                        acc[p * 2 + m][nt] = __builtin_amdgcn_mfma_f32_16x16x32_bf16(
                            af[m][h], bfr[nt][h], acc[p * 2 + m][nt], 0, 0, 0);
            __builtin_amdgcn_s_setprio(0);
            __builtin_amdgcn_s_barrier();
        }
    }

    int bb_ = m0 >> 11;   // batch
#pragma unroll
    for (int nt = 0; nt < 3; nt++) {
        int gc0 = n0 + wn * 48 + nt * 16;            // group base, 16-aligned
        int seg = gc0 >> 10;
        const float* bias = (seg == 0) ? b0 : ((seg == 1) ? b1 : b2);
        int gcl = (gc0 & 1023) + l15;                // column within segment
        float bv = bias[gcl];
        if (seg == 2) {
#pragma unroll
            for (int mt = 0; mt < 8; mt++) {
                int gr = m0 + wm * 128 + mt * 16 + quad * 4;
                int s = gr & 2047;
                u16x4 pk;
#pragma unroll
                for (int r = 0; r < 4; r++) pk[r] = f2bf(acc[mt][nt][r] + bv);
                *(u16x4*)&Vt[(size_t)((bb_ * 16 + (gcl >> 6)) * 64 + (gcl & 63)) * 2048 + s] = pk;
            }
        } else {
            float qs = (seg == 0) ? 0.18033688011112f : 1.0f;  // log2(e)/sqrt(64)
            int gc = gc0 + l15;
#pragma unroll
            for (int mt = 0; mt < 8; mt++) {
                int gr = m0 + wm * 128 + mt * 16 + quad * 4;
#pragma unroll
                for (int r = 0; r < 4; r++)
                    C[(size_t)(gr + r) * 3072 + gc] = f2bf((acc[mt][nt][r] + bv) * qs);
            }
        }
    }
}

// ---------------- gemmo (output proj): 128x64 tile, 2-phase, 512 blocks = 2/CU ----------
// (byte-identical to R10 — verified)
__global__ __launch_bounds__(256) void gemmo(
    const u16* __restrict__ Bt, const float* __restrict__ bias,
    const u16* __restrict__ A, float* __restrict__ C)
{
    __shared__ __align__(16) u16 As[128 * 32];
    __shared__ __align__(16) u16 Bs[64 * 32];
    int tid = threadIdx.x;
    int lane = tid & 63, l15 = lane & 15, quad = lane >> 4;
    int wid = tid >> 6, wm = wid >> 1, wn = wid & 1;
    int lin = blockIdx.x;               // 0..511
    int xcd = lin & 7, idx = lin >> 3;  // idx 0..63
    int mtile = (xcd >> 1) * 8 + (idx & 7);    // 0..31
    int ntile = (xcd & 1) * 8 + (idx >> 3);    // 0..15
    int m0 = mtile * 128, n0 = ntile * 64;

    f32x4 acc[4][2];
#pragma unroll
    for (int i = 0; i < 4; i++)
#pragma unroll
        for (int j = 0; j < 2; j++) { f32x4 z = {0.f, 0.f, 0.f, 0.f}; acc[i][j] = z; }

    int rr = lane >> 2;                       // row within 16-row glds inst
    int cc = (lane & 3) ^ ((rr >> 1) & 3);    // swizzled global chunk
    const u16* abase = A  + (size_t)m0 * 1024;
    const u16* bbase = Bt + (size_t)n0 * 1024;
    int fsw = (l15 >> 1) & 3;                 // frag un-swizzle key

    for (int k0 = 0; k0 < 1024; k0 += 32) {
#pragma unroll
        for (int inst = 0; inst < 2; inst++) {
            int r0 = wid * 32 + inst * 16;
            glds16(&abase[(size_t)(r0 + rr) * 1024 + k0 + cc * 8], &As[r0 * 32]);
        }
        {
            int r0 = wid * 16;
            glds16(&bbase[(size_t)(r0 + rr) * 1024 + k0 + cc * 8], &Bs[r0 * 32]);
        }
        __syncthreads();
        bf16x8 af[4], bf[2];
#pragma unroll
        for (int mt = 0; mt < 4; mt++)
            af[mt] = *(const bf16x8*)&As[(wm * 64 + mt * 16 + l15) * 32 + ((quad ^ fsw) * 8)];
#pragma unroll
        for (int nt = 0; nt < 2; nt++)
            bf[nt] = *(const bf16x8*)&Bs[(wn * 32 + nt * 16 + l15) * 32 + ((quad ^ fsw) * 8)];
#pragma unroll
        for (int mt = 0; mt < 4; mt++)
#pragma unroll
            for (int nt = 0; nt < 2; nt++)
                acc[mt][nt] = __builtin_amdgcn_mfma_f32_16x16x32_bf16(af[mt], bf[nt], acc[mt][nt], 0, 0, 0);
        __syncthreads();
    }
#pragma unroll
    for (int mt = 0; mt < 4; mt++) {
        int gr = m0 + wm * 64 + mt * 16 + quad * 4;
#pragma unroll
        for (int nt = 0; nt < 2; nt++) {
            int gc = n0 + wn * 32 + nt * 16 + l15;
            float bb = bias[gc];
#pragma unroll
            for (int r = 0; r < 4; r++)
                C[(size_t)(gr + r) * 1024 + gc] = acc[mt][nt][r] + bb;
        }
    }
}

// ---------------- MFMA flash attention, v5 (verified best — byte-identical to R10) ----
//  * T15 double-pipeline: iter i = { QK(i) ; exp/pack(i-1) ; PV(i-1) }, named sE/sO.
//  * 4-buffer LDS rotation, 2-tile-ahead prefetch, one barrier per iter, vmcnt(4).
//  * f32 psum denominator, single accumulator per half (R11: zf-C + split-psum
//    REGRESSED +2.3 us, VGPR 116->120 — VALU inst count is not the critical path;
//    keep the compiler's own accumulator scheduling).
//  * XCD-bijective block remap (FETCH 69.7 -> 12.3 MB verified).
__global__ __launch_bounds__(256, 2) void attn(const u16* __restrict__ QKV, // [B*S][3072]
                                               const u16* __restrict__ Vt,  // [bh*64+d][2048]
                                               u16* __restrict__ O)         // [B*S][1024]
{
    __shared__ __align__(16) u16 Ks[4][64 * 64];  // [buf][j][d], XOR-swizzled chunks
    __shared__ __align__(16) u16 Vs[4][64 * 64];  // [buf][d][j], XOR-swizzled chunks
    const int S = 2048, DQ = 3072;
    int tid = threadIdx.x, wid = tid >> 6, lane = tid & 63;
    int l15 = lane & 15, quad = lane >> 4;
    int lin = blockIdx.x;
    int xcd = lin & 7;
    int rest = lin >> 3;            // 0..63
    int qt = rest & 15;
    int g = xcd + 8 * (rest >> 4);  // 0..31
    int h = g & 15, b = g >> 4;
    const u16* base = QKV + (size_t)b * S * DQ + h * 64;
    const u16* Kb = base + 1024;
    const u16* Vtb = Vt + (size_t)((b * 16 + h) * 64) * 2048;
    int q0 = qt * 128 + wid * 32;

    bf16x8 qA0 = *(const bf16x8*)&base[(size_t)(q0 + l15) * DQ + quad * 8];
    bf16x8 qA1 = *(const bf16x8*)&base[(size_t)(q0 + l15) * DQ + 32 + quad * 8];
    bf16x8 qB0 = *(const bf16x8*)&base[(size_t)(q0 + 16 + l15) * DQ + quad * 8];
    bf16x8 qB1 = *(const bf16x8*)&base[(size_t)(q0 + 16 + l15) * DQ + 32 + quad * 8];

    f32x4 oA[4], oB[4];
#pragma unroll
    for (int i = 0; i < 4; i++) { f32x4 z = {0.f, 0.f, 0.f, 0.f}; oA[i] = z; oB[i] = z; }
    float psA = 0.f, psB = 0.f;

    int rr = lane >> 3;
    int cc = (lane & 7) ^ rr;
    int fs7 = l15 & 7;

    auto stage = [&](int t) {
        int kv0 = t << 6, bsel = t & 3;
#pragma unroll
        for (int inst = 0; inst < 2; inst++) {
            int r0 = wid * 16 + inst * 8;
            glds16(&Kb[(size_t)(kv0 + r0 + rr) * DQ + cc * 8], &Ks[bsel][r0 * 64]);
            glds16(&Vtb[(size_t)(r0 + rr) * 2048 + kv0 + cc * 8], &Vs[bsel][r0 * 64]);
        }
    };

    auto qk = [&](int i, f32x4* s) {
        const u16* Kc = &Ks[i & 3][0];
        bf16x8 kfa[4], kfb[4];
#pragma unroll
        for (int t = 0; t < 4; t++) {
            kfa[t] = *(const bf16x8*)&Kc[(t * 16 + l15) * 64 + ((quad ^ fs7) * 8)];
            kfb[t] = *(const bf16x8*)&Kc[(t * 16 + l15) * 64 + (((quad + 4) ^ fs7) * 8)];
        }
#pragma unroll
        for (int t = 0; t < 8; t++) { f32x4 z = {0.f, 0.f, 0.f, 0.f}; s[t] = z; }
        __builtin_amdgcn_s_setprio(1);
#pragma unroll
        for (int t = 0; t < 4; t++) {
            s[t]     = __builtin_amdgcn_mfma_f32_16x16x32_bf16(kfa[t], qA0, s[t], 0, 0, 0);
            s[t]     = __builtin_amdgcn_mfma_f32_16x16x32_bf16(kfb[t], qA1, s[t], 0, 0, 0);
            s[4 + t] = __builtin_amdgcn_mfma_f32_16x16x32_bf16(kfa[t], qB0, s[4 + t], 0, 0, 0);
            s[4 + t] = __builtin_amdgcn_mfma_f32_16x16x32_bf16(kfb[t], qB1, s[4 + t], 0, 0, 0);
        }
        __builtin_amdgcn_s_setprio(0);
    };

    auto fin = [&](int i, f32x4* s) {
        const u16* Vc = &Vs[i & 3][0];
        bf16x8 vfa[4], vfb[4];
#pragma unroll
        for (int dt = 0; dt < 4; dt++) {
            vfa[dt] = *(const bf16x8*)&Vc[(dt * 16 + l15) * 64 + ((quad ^ fs7) * 8)];
            vfb[dt] = *(const bf16x8*)&Vc[(dt * 16 + l15) * 64 + (((quad + 4) ^ fs7) * 8)];
        }
        unsigned wA[4][2], wB[4][2];
#pragma unroll
        for (int t = 0; t < 4; t++) {
            float a0 = __builtin_amdgcn_exp2f(s[t][0]);
            float a1 = __builtin_amdgcn_exp2f(s[t][1]);
            float a2 = __builtin_amdgcn_exp2f(s[t][2]);
            float a3 = __builtin_amdgcn_exp2f(s[t][3]);
            psA += (a0 + a1) + (a2 + a3);
            asm("v_cvt_pk_bf16_f32 %0, %1, %2" : "=v"(wA[t][0]) : "v"(a0), "v"(a1));
            asm("v_cvt_pk_bf16_f32 %0, %1, %2" : "=v"(wA[t][1]) : "v"(a2), "v"(a3));
            float b0_ = __builtin_amdgcn_exp2f(s[4 + t][0]);
            float b1_ = __builtin_amdgcn_exp2f(s[4 + t][1]);
            float b2_ = __builtin_amdgcn_exp2f(s[4 + t][2]);
            float b3_ = __builtin_amdgcn_exp2f(s[4 + t][3]);
            psB += (b0_ + b1_) + (b2_ + b3_);
            asm("v_cvt_pk_bf16_f32 %0, %1, %2" : "=v"(wB[t][0]) : "v"(b0_), "v"(b1_));
            asm("v_cvt_pk_bf16_f32 %0, %1, %2" : "=v"(wB[t][1]) : "v"(b2_), "v"(b3_));
        }
        unsigned a0 = wA[0][0], a2 = wA[1][0]; swap_half(a0, a2);
        unsigned a1 = wA[0][1], a3 = wA[1][1]; swap_half(a1, a3);
        unsigned c0 = wA[2][0], c2 = wA[3][0]; swap_half(c0, c2);
        unsigned c1 = wA[2][1], c3 = wA[3][1]; swap_half(c1, c3);
        u32x4 pdA0 = {a0, a1, a2, a3};
        u32x4 pdA1 = {c0, c1, c2, c3};
        bf16x8 pfA0 = *(bf16x8*)&pdA0;   // P_A[q=l15][j = quad*8 .. +7]
        bf16x8 pfA1 = *(bf16x8*)&pdA1;   // P_A[q=l15][j = 32+quad*8 .. +7]
        unsigned d0 = wB[0][0], d2 = wB[1][0]; swap_half(d0, d2);
        unsigned d1 = wB[0][1], d3 = wB[1][1]; swap_half(d1, d3);
        unsigned e0 = wB[2][0], e2 = wB[3][0]; swap_half(e0, e2);
        unsigned e1 = wB[2][1], e3 = wB[3][1]; swap_half(e1, e3);
        u32x4 pdB0 = {d0, d1, d2, d3};
        u32x4 pdB1 = {e0, e1, e2, e3};
        bf16x8 pfB0 = *(bf16x8*)&pdB0;
        bf16x8 pfB1 = *(bf16x8*)&pdB1;
        __builtin_amdgcn_s_setprio(1);
#pragma unroll
        for (int dt = 0; dt < 4; dt++) {
            oA[dt] = __builtin_amdgcn_mfma_f32_16x16x32_bf16(pfA0, vfa[dt], oA[dt], 0, 0, 0);
            oA[dt] = __builtin_amdgcn_mfma_f32_16x16x32_bf16(pfA1, vfb[dt], oA[dt], 0, 0, 0);
            oB[dt] = __builtin_amdgcn_mfma_f32_16x16x32_bf16(pfB0, vfa[dt], oB[dt], 0, 0, 0);
            oB[dt] = __builtin_amdgcn_mfma_f32_16x16x32_bf16(pfB1, vfb[dt], oB[dt], 0, 0, 0);
        }
        __builtin_amdgcn_s_setprio(0);
    };

    f32x4 sE[8], sO[8];               // two named S-states (even/odd tiles)

    stage(0); stage(1);               // prologue: tiles 0,1 in flight (8 loads)
    asm volatile("s_waitcnt vmcnt(4)");   // tile 0 landed, tile 1 in flight
    __builtin_amdgcn_s_barrier();
    stage(2);
    qk(0, sE);
    for (int j = 0; j < 15; ++j) {
        int i = 2 * j + 1;
        asm volatile("s_waitcnt vmcnt(4)");
        __builtin_amdgcn_s_barrier();
        if (i + 2 < 32) stage(i + 2);
        qk(i, sO);
        fin(i - 1, sE);
        asm volatile("s_waitcnt vmcnt(4)");
        __builtin_amdgcn_s_barrier();
        if (i + 3 < 32) stage(i + 3);
        qk(i + 1, sE);
        fin(i, sO);
    }
    asm volatile("s_waitcnt vmcnt(0)");
    __builtin_amdgcn_s_barrier();
    qk(31, sO);
    fin(30, sE);
    fin(31, sO);                      // epilogue

    psA += __shfl_xor(psA, 16);
    psA += __shfl_xor(psA, 32);
    psB += __shfl_xor(psB, 16);
    psB += __shfl_xor(psB, 32);
#pragma unroll
    for (int r = 0; r < 4; r++) {
        float invA = 1.0f / __shfl(psA, quad * 4 + r);
        size_t rowA = (size_t)(b * S + q0 + quad * 4 + r);
#pragma unroll
        for (int dt = 0; dt < 4; dt++)
            O[rowA * 1024 + h * 64 + dt * 16 + l15] = f2bf(oA[dt][r] * invA);
        float invB = 1.0f / __shfl(psB, quad * 4 + r);
        size_t rowB = rowA + 16;
#pragma unroll
        for (int dt = 0; dt < 4; dt++)
            O[rowB * 1024 + h * 64 + dt * 16 + l15] = f2bf(oB[dt][r] * invB);
    }
}

extern "C" void kernel_launch(void* const* d_in, const int* in_sizes, int n_in,
                              void* d_out, int out_size, void* d_ws, size_t ws_size,
                              hipStream_t stream) {
    const float* x  = (const float*)d_in[0];
    const float* wq = (const float*)d_in[1];
    const float* bq = (const float*)d_in[2];
    const float* wk = (const float*)d_in[3];
    const float* bk = (const float*)d_in[4];
    const float* wv = (const float*)d_in[5];
    const float* bv = (const float*)d_in[6];
    const float* wo = (const float*)d_in[7];
    const float* bo = (const float*)d_in[8];
    float* out = (float*)d_out;

    u16* qkv  = (u16*)d_ws;
    u16* obuf = qkv  + (size_t)4096 * 3072;
    u16* vt   = obuf + (size_t)4096 * 1024;
    u16* wt   = vt   + (size_t)2048 * 2048;
    u16* xb   = wt   + (size_t)4 * 1024 * 1024;

    dim3 tb(256);
    prep<<<dim3(32, 32, 8), tb, 0, stream>>>(wq, wk, wv, wo, x, wt, xb);
    gemm256<<<dim3(256), dim3(512), 0, stream>>>(wt, bq, bk, bv, xb, qkv, vt);
    attn<<<dim3(512), tb, 0, stream>>>(qkv, vt, obuf);
    gemmo<<<dim3(512), tb, 0, stream>>>(wt + (size_t)3 * 1024 * 1024, bo, obuf, out);
}